// Round 5
// baseline (268.011 us; speedup 1.0000x reference)
//
#include <hip/hip_runtime.h>
#include <math.h>

#define HIDDEN 1024
#define INTER  1408
#define NEXP   8
#define NTOK   2048
#define KSPLIT_LEN 704   // INTER/2

typedef short s16x8 __attribute__((ext_vector_type(8)));   // 8 bf16 MFMA operand
typedef float f32x4 __attribute__((ext_vector_type(4)));   // MFMA accumulator

static __device__ __forceinline__ short f2b(float f) {
  union { float f; unsigned u; } v; v.f = f;
  unsigned u = v.u;
  unsigned r = (u + 0x7FFFu + ((u >> 16) & 1u)) >> 16;   // RNE
  return (short)r;
}

// ---------------------------------------------------------------------------
// Transposed-weight layout (chunk-slab form):
//   wT[e][slab][n][8]  (bf16), slab = k/8, n = output column.
// GEMM staging reads logical chunk c of row n at ((kb*4+c)*N + n)*8 elems.
//
// wconv v4: every READ instruction is one fully-contiguous row segment.
// ---------------------------------------------------------------------------
static __device__ __forceinline__ void wconv_full(
    const float* __restrict__ se, short* __restrict__ de, int N,
    int kcu, int col0, int lane, short* lw)
{
  const float* p = se + (size_t)kcu * 8 * N + col0 + 4 * lane;
  float vf[32];                       // vf[4j+c] = row j, col 4l+c
#pragma unroll
  for (int j = 0; j < 8; ++j)
    *(float4*)&vf[4 * j] = *(const float4*)(p + (size_t)j * N);

#pragma unroll
  for (int c = 0; c < 4; ++c) {
    unsigned pk[4];
#pragma unroll
    for (int m = 0; m < 4; ++m) {
      unsigned lo = (unsigned short)f2b(vf[8 * m + c]);       // row 2m
      unsigned hi = (unsigned short)f2b(vf[8 * m + 4 + c]);   // row 2m+1
      pk[m] = lo | (hi << 16);
    }
    int slot = 4 * lane + c;
    int phys = slot ^ ((slot >> 6) & 3);          // uniform 8 lanes/bank-group
    *(uint4*)(lw + phys * 8) = make_uint4(pk[0], pk[1], pk[2], pk[3]);
  }
  uint4 outv[4];
#pragma unroll
  for (int s = 0; s < 4; ++s) {
    int slot = 64 * s + lane;
    int phys = slot ^ s;                          // (slot>>6)&3 == s
    outv[s] = *(const uint4*)(lw + phys * 8);
  }
#pragma unroll
  for (int s = 0; s < 4; ++s)
    *(uint4*)(de + ((size_t)kcu * N + col0 + 64 * s + lane) * 8) = outv[s];
}

static __device__ __forceinline__ void wconv_rem(
    const float* __restrict__ se, short* __restrict__ de, int N,
    int row16, int lane, short* lw)
{
  // rows row16*16 .. +15, cols N-128 .. N-1  (used for N=1408 tail)
  int col0 = N - 128;
  int kcu2 = row16 * 2;
  int li = lane & 31, h2 = lane >> 5;
  const float* p = se + (size_t)(row16 * 16 + 8 * h2) * N + col0 + 4 * li;
  float vf[32];
#pragma unroll
  for (int j = 0; j < 8; ++j)
    *(float4*)&vf[4 * j] = *(const float4*)(p + (size_t)j * N);

#pragma unroll
  for (int c = 0; c < 4; ++c) {
    unsigned pk[4];
#pragma unroll
    for (int m = 0; m < 4; ++m) {
      unsigned lo = (unsigned short)f2b(vf[8 * m + c]);
      unsigned hi = (unsigned short)f2b(vf[8 * m + 4 + c]);
      pk[m] = lo | (hi << 16);
    }
    int slot = h2 * 128 + 4 * li + c;
    int phys = slot ^ ((slot >> 6) & 3);
    *(uint4*)(lw + phys * 8) = make_uint4(pk[0], pk[1], pk[2], pk[3]);
  }
  uint4 outv[4];
#pragma unroll
  for (int s = 0; s < 4; ++s) {
    int slot = (s >> 1) * 128 + (s & 1) * 64 + lane;
    int phys = slot ^ s;
    outv[s] = *(const uint4*)(lw + phys * 8);
  }
#pragma unroll
  for (int s = 0; s < 4; ++s)
    *(uint4*)(de + ((size_t)(kcu2 + (s >> 1)) * N + col0 + (s & 1) * 64 + lane) * 8)
        = outv[s];
}

// ---------------------------------------------------------------------------
// Fused kernel 1: router (blocks [0,512)) + wconv of wg,wu (blocks [512,3328)).
// ---------------------------------------------------------------------------
__global__ __launch_bounds__(256) void router_wconv_gu(
    const float* __restrict__ x, const float* __restrict__ rw,
    const float* __restrict__ wg, const float* __restrict__ wu,
    int* __restrict__ ce, float2* __restrict__ cw, short* __restrict__ xb,
    short* __restrict__ wgT, short* __restrict__ wuT)
{
  __shared__ short lds[4][2048];
  int id = blockIdx.x;
  int wave = threadIdx.x >> 6;
  int lane = threadIdx.x & 63;

  if (id >= 512) {
    // ---- wconv wg/wu: 11264 wave-tasks ----
    int gw = (id - 512) * 4 + wave;
    int mat = gw / 5632;              // 0: wg, 1: wu
    int r = gw - mat * 5632;
    int e = r / 704;
    int t = r - e * 704;
    const float* se = (mat == 0 ? wg : wu) + (size_t)e * (HIDDEN * INTER);
    short*       de = (mat == 0 ? wgT : wuT) + (size_t)e * (HIDDEN * INTER);
    short* lw = lds[wave];
    if (t < 640) wconv_full(se, de, INTER, t / 5, (t % 5) * 256, lane, lw);
    else         wconv_rem (se, de, INTER, t - 640, lane, lw);
    return;
  }

  // ---- router: one wave per token, fp32 exact ----
  int t = id * 4 + wave;
  const float* xt = x + (size_t)t * HIDDEN;
  float xr[16];
#pragma unroll
  for (int i = 0; i < 16; ++i) xr[i] = xt[lane + 64 * i];

  short* xo = xb + (size_t)t * HIDDEN;
#pragma unroll
  for (int i = 0; i < 16; ++i) xo[lane + 64 * i] = f2b(xr[i]);

  float logits[NEXP];
#pragma unroll
  for (int e = 0; e < NEXP; ++e) {
    const float* w = rw + e * HIDDEN;
    float acc = 0.f;
#pragma unroll
    for (int i = 0; i < 16; ++i) acc = fmaf(xr[i], w[lane + 64 * i], acc);
#pragma unroll
    for (int off = 32; off > 0; off >>= 1) acc += __shfl_xor(acc, off);
    logits[e] = acc;
  }
  if (lane == 0) {
    float mx = logits[0];
#pragma unroll
    for (int e = 1; e < NEXP; ++e) mx = fmaxf(mx, logits[e]);
    float p[NEXP];
#pragma unroll
    for (int e = 0; e < NEXP; ++e) p[e] = expf(logits[e] - mx);
    int i0 = 0;
#pragma unroll
    for (int e = 1; e < NEXP; ++e) if (p[e] > p[i0]) i0 = e;
    int i1 = (i0 == 0) ? 1 : 0;
#pragma unroll
    for (int e = 0; e < NEXP; ++e) { if (e != i0 && p[e] > p[i1]) i1 = e; }
    float denom = p[i0] + p[i1];
    ce[t] = i0 | (i1 << 8);
    cw[t] = make_float2(p[i0] / denom, p[i1] / denom);
  }
}

// ---------------------------------------------------------------------------
// Router phase 2: one block per expert. Deterministic compaction (stable in
// token order) via register histogram + LDS scan.
// ---------------------------------------------------------------------------
__global__ __launch_bounds__(256) void build_lists(
    const int* __restrict__ ce, const float2* __restrict__ cw,
    int* __restrict__ counts, int* __restrict__ base,
    int* __restrict__ tok_list, float* __restrict__ w_list)
{
  int e = blockIdx.x;          // 0..7
  int tid = threadIdx.x;       // each thread owns tokens [8*tid, 8*tid+8)
  __shared__ int hall[256][8];
  __shared__ int hsum[8];
  __shared__ int scan[256];

  int cloc[8];                 // cached choices
  int h[8] = {0,0,0,0,0,0,0,0};
  int myc = 0;
#pragma unroll
  for (int j = 0; j < 8; ++j) {
    int c = ce[tid * 8 + j];
    cloc[j] = c;
    int e0 = c & 255, e1 = (c >> 8) & 255;
    h[e0]++; h[e1]++;
    myc += (e0 == e) + (e1 == e);
  }
#pragma unroll
  for (int k = 0; k < 8; ++k) hall[tid][k] = h[k];
  scan[tid] = myc;
  __syncthreads();

  if (tid < 8) {
    int s = 0;
    for (int i = 0; i < 256; ++i) s += hall[i][tid];
    hsum[tid] = s;
  }
  // Hillis-Steele inclusive scan over per-thread counts
  int v = myc;
  for (int off = 1; off < 256; off <<= 1) {
    int prev = (tid >= off) ? scan[tid - off] : 0;
    __syncthreads();
    v = v + prev;
    scan[tid] = v;
    __syncthreads();
  }
  int pos = v - myc;           // exclusive prefix = my first slot

  if (tid == 0) {
    int b = 0;
    for (int k = 0; k < e; ++k) b += hsum[k];
    base[e] = b;
    counts[e] = hsum[e];
  }

#pragma unroll
  for (int j = 0; j < 8; ++j) {
    int t = tid * 8 + j;
    int c = cloc[j];
    int e0 = c & 255, e1 = (c >> 8) & 255;
    if (e0 == e) {
      float2 w = cw[t];
      tok_list[e * NTOK + pos] = t;                // slot 0
      w_list[e * NTOK + pos] = w.x;
      pos++;
    } else if (e1 == e) {
      float2 w = cw[t];
      tok_list[e * NTOK + pos] = t | (1 << 16);    // slot 1
      w_list[e * NTOK + pos] = w.y;
      pos++;
    }
  }
}

// ---------------------------------------------------------------------------
// Fused kernel 2: wconv of wd (blocks [0,1408)) + gateup (blocks [1408,4224)).
// gateup r5: tile M=64 N=128 (was 128x128). cnt~512/expert meant only 352
// active 128-tiles -> 1.4 blocks/CU -> Occupancy 15%, MfmaUtil 15% (r4 PMC).
// M=64 doubles active blocks to 704 and halves LDS+acc so 3 blocks/CU
// co-reside; barrier drain of one block hides under another's MFMA.
// 4 waves (2x2), per-wave 32x64 output: acc[2][4] for gate AND up.
// ---------------------------------------------------------------------------
__global__ __launch_bounds__(256, 3) void gateup_wconv_d(
    const short* __restrict__ xb, const short* __restrict__ wgT,
    const short* __restrict__ wuT,
    const float* __restrict__ wd, short* __restrict__ wdT,
    const int* __restrict__ counts, const int* __restrict__ base,
    const int* __restrict__ tok_list, short* __restrict__ hbuf)
{
  __shared__ __align__(16) char smem[20736];  // A 4K + Bg 8K + Bu 8K + toks 256
  int id0 = blockIdx.x;
  int tid = threadIdx.x;

  if (id0 < 1408) {
    // ---- wconv wd: 5632 wave-tasks, N = HIDDEN ----
    int gw = id0 * 4 + (tid >> 6);
    int lane = tid & 63;
    int e = gw / 704;
    int t = gw - e * 704;
    const float* se = wd + (size_t)e * (HIDDEN * INTER);
    short*       de = wdT + (size_t)e * (HIDDEN * INTER);
    short* lw = (short*)smem + (tid >> 6) * 2048;
    wconv_full(se, de, HIDDEN, t >> 2, (t & 3) * 256, lane, lw);
    return;
  }

  // ---- gateup: grid 8 xcd * 32 m * 11 g-hi = 2816 ----
  int id = id0 - 1408;
  int xcd = id & 7;
  int rest = id >> 3;
  int mslot = rest & 31;
  int g = (rest >> 5) * 8 + xcd;
  int e = g / 11;
  int n0 = (g - e * 11) * 128;
  int cnt = counts[e];
  int m0 = mslot * 64;
  if (m0 >= cnt) return;

  short* As = (short*)smem;            // 64*32
  short* Bg = (short*)(smem + 4096);   // 128*32
  short* Bu = (short*)(smem + 12288);  // 128*32
  int* toks = (int*)(smem + 20480);

  if (tid < 64) {
    int r = m0 + tid;
    toks[tid] = tok_list[e * NTOK + (r < cnt ? r : cnt - 1)] & 0xFFFF;
  }
  __syncthreads();

  // A staging: thread -> (row tid>>2, phys chunk tid&3); 16B per thread
  int ar = tid >> 2, ap = tid & 3;
  int ac = ap ^ ((ar >> 1) & 3);                 // logical chunk
  const short* gA = xb + (size_t)toks[ar] * HIDDEN + 8 * ac;
  short* wA = &As[ar * 32 + ap * 8];

  // B staging: thread -> (row tid>>1, chunk pair tid&1); 32B per thread
  int sr = tid >> 1;
  int h = tid & 1;
  int key = (sr >> 1) & 3;
  int pair = ((2 * h) ^ key) >> 1;               // which 32B global block
  int sw = (key & 1) * 8;                        // swap c0/c1 on write
  size_t ebase = (size_t)e * (HIDDEN * INTER);
  size_t boff = (size_t)(2 * pair) * (INTER * 8) + (size_t)(n0 + sr) * 8;
  const short* gGb = wgT + ebase + boff;
  const short* gUb = wuT + ebase + boff;
  short* wG0 = &Bg[sr * 32 + h * 16 + sw];
  short* wG1 = &Bg[sr * 32 + h * 16 + (8 - sw)];
  short* wU0 = &Bu[sr * 32 + h * 16 + sw];
  short* wU1 = &Bu[sr * 32 + h * 16 + (8 - sw)];

  int wv = tid >> 6, lane = tid & 63;
  int wm = wv & 1, wn = wv >> 1;
  int q = lane >> 4, ml = lane & 15;
  int chk = q ^ ((ml >> 1) & 3);
  const short* ard = &As[(wm * 32 + ml) * 32 + chk * 8];
  const short* grd = &Bg[(wn * 64 + ml) * 32 + chk * 8];
  const short* urd = &Bu[(wn * 64 + ml) * 32 + chk * 8];

  f32x4 accg[2][4], accu[2][4];
#pragma unroll
  for (int i = 0; i < 2; ++i)
#pragma unroll
    for (int j = 0; j < 4; ++j) { accg[i][j] = (f32x4)0.f; accu[i][j] = (f32x4)0.f; }

  s16x8 a0 = *(const s16x8*)(gA);
  s16x8 g0 = *(const s16x8*)(gGb);    s16x8 g1 = *(const s16x8*)(gGb + INTER * 8);
  s16x8 u0 = *(const s16x8*)(gUb);    s16x8 u1 = *(const s16x8*)(gUb + INTER * 8);

  for (int k0 = 0; k0 < HIDDEN; k0 += 32) {
    __syncthreads();
    *(s16x8*)wA = a0;
    *(s16x8*)wG0 = g0; *(s16x8*)wG1 = g1;
    *(s16x8*)wU0 = u0; *(s16x8*)wU1 = u1;
    __syncthreads();

    int kn = (k0 + 32) & (HIDDEN - 1);
    size_t kboff = (size_t)(kn >> 5) * (4 * INTER * 8);
    a0 = *(const s16x8*)(gA + kn);
    g0 = *(const s16x8*)(gGb + kboff);     g1 = *(const s16x8*)(gGb + kboff + INTER * 8);
    u0 = *(const s16x8*)(gUb + kboff);     u1 = *(const s16x8*)(gUb + kboff + INTER * 8);

    s16x8 af[2], gf[4], uf[4];
#pragma unroll
    for (int i = 0; i < 2; ++i) af[i] = *(const s16x8*)(ard + i * 16 * 32);
#pragma unroll
    for (int j = 0; j < 4; ++j) {
      gf[j] = *(const s16x8*)(grd + j * 16 * 32);
      uf[j] = *(const s16x8*)(urd + j * 16 * 32);
    }
#pragma unroll
    for (int i = 0; i < 2; ++i)
#pragma unroll
      for (int j = 0; j < 4; ++j) {
        accg[i][j] = __builtin_amdgcn_mfma_f32_16x16x32_bf16(af[i], gf[j], accg[i][j], 0, 0, 0);
        accu[i][j] = __builtin_amdgcn_mfma_f32_16x16x32_bf16(af[i], uf[j], accu[i][j], 0, 0, 0);
      }
  }

  int hb = base[e];
#pragma unroll
  for (int i = 0; i < 2; ++i)
#pragma unroll
    for (int ii = 0; ii < 4; ++ii) {
      int r = m0 + wm * 32 + i * 16 + q * 4 + ii;
      if (r < cnt) {
        short* hp = hbuf + (size_t)(hb + r) * INTER + n0 + wn * 64 + ml;
#pragma unroll
        for (int j = 0; j < 4; ++j) {
          float gg = accg[i][j][ii], uu = accu[i][j][ii];
          float hh = (gg / (1.f + __expf(-gg))) * uu;
          hp[j * 16] = f2b(hh);
        }
      }
    }
}

// ---------------------------------------------------------------------------
// Phase B: Y = H @ Wd, K-split x2, tile M=64 N=128 (same occupancy fix as
// gateup: 1024 active blocks, 12.5KB LDS, 4 blocks/CU).
// ---------------------------------------------------------------------------
__global__ __launch_bounds__(256, 4) void down_mfma(
    const short* __restrict__ hbuf, const short* __restrict__ wdT,
    const int* __restrict__ counts, const int* __restrict__ base,
    const int* __restrict__ tok_list, const float* __restrict__ w_list,
    float* __restrict__ ybuf)
{
  // grid = 8 xcd * 32 m * 16 g-hi = 4096; g = (e,ks,n) in 0..127
  int id = blockIdx.x;
  int xcd = id & 7;
  int rest = id >> 3;
  int mslot = rest & 31;
  int g = (rest >> 5) * 8 + xcd;
  int e = g >> 4;
  int ks = (g >> 3) & 1;
  int n0 = (g & 7) * 128;
  int cnt = counts[e];
  int m0 = mslot * 64;
  if (m0 >= cnt) return;

  __shared__ short As[64 * 32];
  __shared__ short Bs[128 * 32];

  int tid = threadIdx.x;
  int hb = base[e];
  int kbeg = ks * KSPLIT_LEN, kend = kbeg + KSPLIT_LEN;

  // A staging: thread -> (row tid>>2, phys chunk tid&3)
  int ar = tid >> 2, ap = tid & 3;
  int ac = ap ^ ((ar >> 1) & 3);
  int ra = m0 + ar; if (ra >= cnt) ra = cnt - 1;
  const short* gA = hbuf + (size_t)(hb + ra) * INTER + 8 * ac;
  short* wA = &As[ar * 32 + ap * 8];

  // B staging
  int sr = tid >> 1;
  int h = tid & 1;
  int key = (sr >> 1) & 3;
  int pair = ((2 * h) ^ key) >> 1;
  int sw = (key & 1) * 8;
  size_t ebase = (size_t)e * (HIDDEN * INTER);
  const short* gBb = wdT + ebase + (size_t)(2 * pair) * (HIDDEN * 8)
                         + (size_t)(n0 + sr) * 8;
  short* wB0 = &Bs[sr * 32 + h * 16 + sw];
  short* wB1 = &Bs[sr * 32 + h * 16 + (8 - sw)];

  int wv = tid >> 6, lane = tid & 63;
  int wm = wv & 1, wn = wv >> 1;
  int q = lane >> 4, ml = lane & 15;
  int chk = q ^ ((ml >> 1) & 3);
  const short* ard = &As[(wm * 32 + ml) * 32 + chk * 8];
  const short* brd = &Bs[(wn * 64 + ml) * 32 + chk * 8];

  f32x4 acc[2][4];
#pragma unroll
  for (int i = 0; i < 2; ++i)
#pragma unroll
    for (int j = 0; j < 4; ++j) acc[i][j] = (f32x4)0.f;

  size_t kboff0 = (size_t)(kbeg >> 5) * (4 * HIDDEN * 8);
  s16x8 a0 = *(const s16x8*)(gA + kbeg);
  s16x8 b0 = *(const s16x8*)(gBb + kboff0);
  s16x8 b1 = *(const s16x8*)(gBb + kboff0 + HIDDEN * 8);

  for (int k0 = kbeg; k0 < kend; k0 += 32) {
    __syncthreads();
    *(s16x8*)wA = a0;
    *(s16x8*)wB0 = b0; *(s16x8*)wB1 = b1;
    __syncthreads();

    int kn = k0 + 32; if (kn >= kend) kn = kbeg;
    size_t kboff = (size_t)(kn >> 5) * (4 * HIDDEN * 8);
    a0 = *(const s16x8*)(gA + kn);
    b0 = *(const s16x8*)(gBb + kboff);
    b1 = *(const s16x8*)(gBb + kboff + HIDDEN * 8);

    s16x8 af[2], bf[4];
#pragma unroll
    for (int i = 0; i < 2; ++i) af[i] = *(const s16x8*)(ard + i * 16 * 32);
#pragma unroll
    for (int j = 0; j < 4; ++j) bf[j] = *(const s16x8*)(brd + j * 16 * 32);
#pragma unroll
    for (int i = 0; i < 2; ++i)
#pragma unroll
      for (int j = 0; j < 4; ++j)
        acc[i][j] = __builtin_amdgcn_mfma_f32_16x16x32_bf16(af[i], bf[j], acc[i][j], 0, 0, 0);
  }

#pragma unroll
  for (int i = 0; i < 2; ++i)
#pragma unroll
    for (int ii = 0; ii < 4; ++ii) {
      int r = m0 + wm * 32 + i * 16 + q * 4 + ii;
      if (r < cnt) {
        int ent = tok_list[e * NTOK + r];
        int tok = ent & 0xFFFF, slot = ent >> 16;
        float wgt = w_list[e * NTOK + r];
        float* yp = ybuf + ((size_t)(slot * 2 + ks) * NTOK + tok) * HIDDEN
                    + n0 + wn * 64 + ml;
#pragma unroll
        for (int j = 0; j < 4; ++j)
          yp[j * 16] = acc[i][j][ii] * wgt;
      }
    }
}

// ---------------------------------------------------------------------------
// out = sum of 4 ybuf slabs (every element written -> no out memset needed)
// ---------------------------------------------------------------------------
__global__ __launch_bounds__(256) void combine_kernel(
    const float* __restrict__ ybuf, float* __restrict__ out)
{
  size_t i = (size_t)blockIdx.x * 256 + threadIdx.x;
  const size_t S = (size_t)NTOK * HIDDEN / 4;
  float4 a = ((const float4*)ybuf)[i];
  float4 b = ((const float4*)ybuf)[i + S];
  float4 c = ((const float4*)ybuf)[i + 2 * S];
  float4 d = ((const float4*)ybuf)[i + 3 * S];
  float4 o;
  o.x = (a.x + b.x) + (c.x + d.x);
  o.y = (a.y + b.y) + (c.y + d.y);
  o.z = (a.z + b.z) + (c.z + d.z);
  o.w = (a.w + b.w) + (c.w + d.w);
  ((float4*)out)[i] = o;
}

// ---------------------------------------------------------------------------
// ws layout (bytes):
//   0..32           counts[8]
//   32..64          base[8]
//   64..65600       tok_list[8][2048]  (token | slot<<16)
//   65600..131136   w_list[8][2048]
//   131136..139328  ce[2048]
//   139328..155712  cw[2048] float2
//   155712          xb   bf16 [2048][1024]      (4 MB)
//   +4 MB           wgT  bf16 slabs             (23.07 MB) } ybuf[4] (32 MB
//   +23.07 MB       wuT  bf16 slabs             (23.07 MB) } fp32) aliases
//                                                          } wgT+wuT after
//                                                          } gateup completes
//   +23.07 MB       wdT  bf16 slabs
//   +23.07 MB       hbuf bf16 [4096][1408]      (11.5 MB)
//   total ~85.2 MB
// ---------------------------------------------------------------------------
extern "C" void kernel_launch(void* const* d_in, const int* in_sizes, int n_in,
                              void* d_out, int out_size, void* d_ws, size_t ws_size,
                              hipStream_t stream)
{
  const float* x  = (const float*)d_in[0];
  const float* rw = (const float*)d_in[1];
  const float* wg = (const float*)d_in[2];
  const float* wu = (const float*)d_in[3];
  const float* wd = (const float*)d_in[4];
  float* out = (float*)d_out;

  char* ws = (char*)d_ws;
  int*    counts   = (int*)(ws);
  int*    base     = (int*)(ws + 32);
  int*    tok_list = (int*)(ws + 64);
  float*  w_list   = (float*)(ws + 64 + NEXP * NTOK * 4);
  size_t off = 64 + 2 * (size_t)NEXP * NTOK * 4;
  int*    ce = (int*)(ws + off);     off += NTOK * 4;
  float2* cw = (float2*)(ws + off);  off += NTOK * 8;
  short* xb  = (short*)(ws + off);  off += (size_t)NTOK * HIDDEN * 2;
  short* wgT = (short*)(ws + off);  off += (size_t)NEXP * HIDDEN * INTER * 2;
  short* wuT = (short*)(ws + off);  off += (size_t)NEXP * HIDDEN * INTER * 2;
  short* wdT = (short*)(ws + off);  off += (size_t)NEXP * HIDDEN * INTER * 2;
  short* hbuf = (short*)(ws + off);
  float* ybuf = (float*)wgT;   // wgT+wuT dead after gateup; 32 MB fits in 46 MB

  router_wconv_gu<<<512 + 2816, 256, 0, stream>>>(x, rw, wg, wu, ce, cw, xb, wgT, wuT);
  build_lists<<<NEXP, 256, 0, stream>>>(ce, cw, counts, base, tok_list, w_list);

  gateup_wconv_d<<<1408 + 2816, 256, 0, stream>>>(
      xb, wgT, wuT, wd, wdT, counts, base, tok_list, hbuf);

  down_mfma<<<4096, 256, 0, stream>>>(hbuf, wdT, counts, base, tok_list, w_list, ybuf);

  combine_kernel<<<(NTOK * HIDDEN / 4) / 256, 256, 0, stream>>>(ybuf, out);
}